// Round 6
// baseline (22258.388 us; speedup 1.0000x reference)
//
#include <hip/hip_runtime.h>
#include <math.h>

#define D_MODEL 1024
#define NHEADS 16
#define DHEAD 64
#define NLAYERS 12
#define VOCAB 32000
#define BATCH 8
#define SEQ 512
#define NTOK (BATCH*SEQ)   // 4096

using short8 = __attribute__((ext_vector_type(8))) short;
using fx4    = __attribute__((ext_vector_type(4))) float;

__device__ __forceinline__ unsigned short f2bf(float f) {
  union { float f; unsigned u; } v; v.f = f;
  unsigned r = v.u + 0x7FFFu + ((v.u >> 16) & 1u);
  return (unsigned short)(r >> 16);
}
__device__ __forceinline__ float bf2f(unsigned short u) {
  union { unsigned u; float f; } v; v.u = ((unsigned)u) << 16;
  return v.f;
}
__device__ __forceinline__ void split2(float x, unsigned short& h, unsigned short& l) {
  h = f2bf(x);
  l = f2bf(x - bf2f(h));
}
__device__ __forceinline__ float gelu_exact(float x) {
  return 0.5f * x * (1.f + erff(x * 0.70710678118654752f));
}

// ---------------- weight conversion (hi/lo split planes) ----------------

// QKV fused: out [12][3072][2048] bf16 (hi cols [0,1024), lo cols [1024,2048))
__global__ __launch_bounds__(256) void cvt_qkv_split(const float* __restrict__ WQ,
    const float* __restrict__ WK, const float* __restrict__ WV,
    unsigned short* __restrict__ out)
{
  const long total = 12L * 3072 * 256;     // float4 units
  const long stride = (long)gridDim.x * blockDim.x;
  for (long t = (long)blockIdx.x * blockDim.x + threadIdx.x; t < total; t += stride) {
    const long layer = t / (3072L * 256);
    const long rem = t - layer * (3072L * 256);
    const int n = (int)(rem >> 8);
    const int k4 = (int)(rem & 255);
    const float* src;
    if (n < 1024)       src = WQ + ((size_t)layer * 1024 + n) * 1024;
    else if (n < 2048)  src = WK + ((size_t)layer * 1024 + (n - 1024)) * 1024;
    else                src = WV + ((size_t)layer * 1024 + (n - 2048)) * 1024;
    const float4 v = *(const float4*)(src + k4 * 4);
    ushort4 h, l; unsigned short a, b;
    split2(v.x, a, b); h.x = a; l.x = b;
    split2(v.y, a, b); h.y = a; l.y = b;
    split2(v.z, a, b); h.z = a; l.z = b;
    split2(v.w, a, b); h.w = a; l.w = b;
    unsigned short* dst = out + ((size_t)layer * 3072 + n) * 2048 + k4 * 4;
    *(ushort4*)dst = h;
    *(ushort4*)(dst + 1024) = l;
  }
}

// generic (no transpose): in [rows][K] f32 -> out [rows][2K] hi|lo
__global__ __launch_bounds__(256) void cvt_split(const float* __restrict__ in,
    unsigned short* __restrict__ out, long rows, int K)
{
  const int K4 = K >> 2;
  const long total = rows * K4;
  const long stride = (long)gridDim.x * blockDim.x;
  for (long t = (long)blockIdx.x * blockDim.x + threadIdx.x; t < total; t += stride) {
    const long r = t / K4;
    const int k4 = (int)(t - r * K4);
    const float4 v = *(const float4*)(in + r * K + k4 * 4);
    ushort4 h, l; unsigned short a, b;
    split2(v.x, a, b); h.x = a; l.x = b;
    split2(v.y, a, b); h.y = a; l.y = b;
    split2(v.z, a, b); h.z = a; l.z = b;
    split2(v.w, a, b); h.w = a; l.w = b;
    unsigned short* dst = out + r * 2 * K + k4 * 4;
    *(ushort4*)dst = h;
    *(ushort4*)(dst + K) = l;
  }
}

// in: [R][C] f32 (per layer, blockIdx.z), out: [C][2R] hi|lo
__global__ __launch_bounds__(256) void transpose_cvt_split(const float* __restrict__ in,
    unsigned short* __restrict__ out, int R, int C)
{
  __shared__ float tile[32][33];
  in  += (size_t)blockIdx.z * R * C;
  out += (size_t)blockIdx.z * 2 * R * C;
  const int r0 = blockIdx.y * 32, c0 = blockIdx.x * 32;
  const int tr = threadIdx.x >> 5, tc = threadIdx.x & 31;
#pragma unroll
  for (int i = 0; i < 4; ++i)
    tile[tr + i * 8][tc] = in[(size_t)(r0 + tr + i * 8) * C + c0 + tc];
  __syncthreads();
#pragma unroll
  for (int i = 0; i < 4; ++i) {
    unsigned short h, l;
    split2(tile[tc][tr + i * 8], h, l);
    const size_t o = (size_t)(c0 + tr + i * 8) * 2 * R + r0 + tc;
    out[o] = h;
    out[o + R] = l;
  }
}

// in: [R][C] f32, out: [C][R] bf16 (hi only — devocab weight)
__global__ __launch_bounds__(256) void transpose_cvt(const float* __restrict__ in,
    unsigned short* __restrict__ out, int R, int C)
{
  __shared__ float tile[32][33];
  const int r0 = blockIdx.y * 32, c0 = blockIdx.x * 32;
  const int tr = threadIdx.x >> 5, tc = threadIdx.x & 31;
#pragma unroll
  for (int i = 0; i < 4; ++i)
    tile[tr + i * 8][tc] = in[(size_t)(r0 + tr + i * 8) * C + c0 + tc];
  __syncthreads();
#pragma unroll
  for (int i = 0; i < 4; ++i)
    out[(size_t)(c0 + tr + i * 8) * R + r0 + tc] = f2bf(tile[tc][tr + i * 8]);
}

// ---------------- embedding + positional ----------------

__global__ __launch_bounds__(256) void embed_kernel(const int* __restrict__ ids,
    const float* __restrict__ Wv, float* __restrict__ x)
{
  const int t = blockIdx.x;
  const int id = ids[t];
  const int l = t & (SEQ - 1);
  const float pos = (float)l;
  const int d0 = threadIdx.x * 4;
  const float i0 = (float)(d0 >> 1);
  const float f0 = expf(-0.017988946039016f * i0);
  const float f1 = expf(-0.017988946039016f * (i0 + 1.f));
  const float a0 = pos * f0, a1 = pos * f1;
  float4 v;
  v.x = Wv[(size_t)(d0 + 0) * VOCAB + id] + sinf(a0);
  v.y = Wv[(size_t)(d0 + 1) * VOCAB + id] + cosf(a0);
  v.z = Wv[(size_t)(d0 + 2) * VOCAB + id] + sinf(a1);
  v.w = Wv[(size_t)(d0 + 3) * VOCAB + id] + cosf(a1);
  ((float4*)(x + (size_t)t * 1024))[threadIdx.x] = v;
}

// ---------------- layernorm (f32 in -> hi/lo bf16 planes out, stride 2048) ----------------

__global__ __launch_bounds__(256) void layernorm_split(const float* __restrict__ x,
    const float* __restrict__ g, const float* __restrict__ be,
    unsigned short* __restrict__ out)
{
  const int row = blockIdx.x;
  const float4 v = ((const float4*)(x + (size_t)row * 1024))[threadIdx.x];
  float s = v.x + v.y + v.z + v.w;
  float q = v.x * v.x + v.y * v.y + v.z * v.z + v.w * v.w;
#pragma unroll
  for (int o = 32; o; o >>= 1) { s += __shfl_xor(s, o); q += __shfl_xor(q, o); }
  __shared__ float ss[4], qq[4];
  const int w = threadIdx.x >> 6;
  if ((threadIdx.x & 63) == 0) { ss[w] = s; qq[w] = q; }
  __syncthreads();
  s = ss[0] + ss[1] + ss[2] + ss[3];
  q = qq[0] + qq[1] + qq[2] + qq[3];
  const float mean = s * (1.f / 1024.f);
  const float var = q * (1.f / 1024.f) - mean * mean;
  const float rstd = rsqrtf(var + 1e-5f);
  const float4 gv = ((const float4*)g)[threadIdx.x];
  const float4 bv = ((const float4*)be)[threadIdx.x];
  float4 y;
  y.x = (v.x - mean) * rstd * gv.x + bv.x;
  y.y = (v.y - mean) * rstd * gv.y + bv.y;
  y.z = (v.z - mean) * rstd * gv.z + bv.z;
  y.w = (v.w - mean) * rstd * gv.w + bv.w;
  ushort4 h4, l4; unsigned short a, b;
  split2(y.x, a, b); h4.x = a; l4.x = b;
  split2(y.y, a, b); h4.y = a; l4.y = b;
  split2(y.z, a, b); h4.z = a; l4.z = b;
  split2(y.w, a, b); h4.w = a; l4.w = b;
  unsigned short* dst = out + (size_t)row * 2048 + threadIdx.x * 4;
  *(ushort4*)dst = h4;
  *(ushort4*)(dst + 1024) = l4;
}

// ---------------- split GEMM: C[M,N] = A[M,K] * B[N,K]^T, near-f32 precision ----------------
// SPLIT==3: A hi/lo (stride 2K), B hi/lo (stride 2K): Ah*Bh + Al*Bh + Ah*Bl
// SPLIT==2: A hi/lo (stride 2K), B hi only (stride K): Ah*Bh + Al*Bh
// EPI 0: f32 = acc                        (QKV -> qkvf; devocab -> d_out)
// EPI 2: f32 = res + acc                  (W_O)
// EPI 3: hi/lo = gelu(acc + bias), stride 2N (W_up)
// EPI 4: f32 = res + acc + bias           (W_down)

template<int EPI, int SPLIT>
__global__ __launch_bounds__(256) void gemm_bt(
    const unsigned short* __restrict__ A, const unsigned short* __restrict__ B,
    float* __restrict__ Cf, unsigned short* __restrict__ Cb,
    const float* __restrict__ bias, const float* __restrict__ res,
    int M, int N, int K)
{
  __shared__ __align__(16) unsigned short As[128 * 64];
  __shared__ __align__(16) unsigned short Bs[128 * 64];
  const int tid = threadIdx.x;
  const int lane = tid & 63, w = tid >> 6;
  const int wr = w >> 1, wc = w & 1;
  const int brow = blockIdx.y * 128, bcol = blockIdx.x * 128;
  const int SA = 2 * K;                         // A always hi/lo
  const int SB = (SPLIT == 3) ? 2 * K : K;
  const int KEFF = SPLIT * K;
  fx4 acc[4][4];
  const fx4 zero = {0.f, 0.f, 0.f, 0.f};
#pragma unroll
  for (int i = 0; i < 4; ++i)
#pragma unroll
    for (int j = 0; j < 4; ++j) acc[i][j] = zero;

  const unsigned short* Ab = A + (size_t)brow * SA;
  const unsigned short* Bb = B + (size_t)bcol * SB;

  for (int k0 = 0; k0 < KEFF; k0 += 64) {
    int ka, kb;
    if (SPLIT == 3) {
      ka = (k0 < 2 * K) ? k0 : k0 - 2 * K;      // hi | lo | hi
      kb = (k0 < K) ? k0 : k0 - K;              // hi | hi | lo
    } else {
      ka = k0;                                  // hi | lo
      kb = (k0 < K) ? k0 : k0 - K;              // hi | hi
    }
#pragma unroll
    for (int it = 0; it < 4; ++it) {
      int idx = it * 256 + tid;          // 0..1023
      int r = idx >> 3, c = (idx & 7) * 8;
      *(short8*)&As[idx * 8] = *(const short8*)&Ab[(size_t)r * SA + ka + c];
      *(short8*)&Bs[idx * 8] = *(const short8*)&Bb[(size_t)r * SB + kb + c];
    }
    __syncthreads();
#pragma unroll
    for (int kk = 0; kk < 2; ++kk) {
      short8 af[4], bfv[4];
      const int kof = kk * 32 + (lane >> 4) * 8;
#pragma unroll
      for (int f = 0; f < 4; ++f)
        af[f] = *(const short8*)&As[(wr * 64 + f * 16 + (lane & 15)) * 64 + kof];
#pragma unroll
      for (int f = 0; f < 4; ++f)
        bfv[f] = *(const short8*)&Bs[(wc * 64 + f * 16 + (lane & 15)) * 64 + kof];
#pragma unroll
      for (int i = 0; i < 4; ++i)
#pragma unroll
        for (int j = 0; j < 4; ++j)
          acc[i][j] = __builtin_amdgcn_mfma_f32_16x16x32_bf16(af[i], bfv[j], acc[i][j], 0, 0, 0);
    }
    __syncthreads();
  }

  // C/D layout: col = lane&15, row = (lane>>4)*4 + reg
  const int r0 = brow + wr * 64 + (lane >> 4) * 4;
  const int c0 = bcol + wc * 64 + (lane & 15);
#pragma unroll
  for (int i = 0; i < 4; ++i) {
#pragma unroll
    for (int j = 0; j < 4; ++j) {
      const int cc = c0 + j * 16;
#pragma unroll
      for (int qi = 0; qi < 4; ++qi) {
        const int rr = r0 + i * 16 + qi;
        const size_t off = (size_t)rr * N + cc;
        const float val = acc[i][j][qi];
        if (EPI == 0) {
          Cf[off] = val;
        } else if (EPI == 2) {
          Cf[off] = res[off] + val;
        } else if (EPI == 3) {
          unsigned short hh, ll;
          split2(gelu_exact(val + bias[cc]), hh, ll);
          Cb[(size_t)rr * (2 * N) + cc] = hh;
          Cb[(size_t)rr * (2 * N) + N + cc] = ll;
        } else {
          Cf[off] = res[off] + val + bias[cc];
        }
      }
    }
  }
}

// ---------------- attention: flash-style online softmax, all f32 ----------------
// grid.x = B*H*4 ; block = 512 (8 waves). Each block: (b, h, 128-row tile).
// Per wave: 16 rows (l = row0 + k*8 + w), lane = head dim. Online (m, sum, acc)
// state per row lives in registers (statically indexed via unroll). K/V staged
// per 128-key chunk in f32; K slot-swizzled (G4), V row-major (conflict-free read).
// qkvf: [NTOK][3072] f32 (q|k|v). out2: [NTOK][2048] bf16 hi|lo planes.

__global__ __launch_bounds__(512) void attn_kernel(
    const float* __restrict__ qkvf,
    const int* __restrict__ amask,
    unsigned short* __restrict__ out2)
{
  const int bid = blockIdx.x;
  const int rt = bid & 3;
  const int h  = (bid >> 2) & 15;
  const int b  = bid >> 6;
  const int row0 = rt * 128;

  __shared__ __align__(16) float Kc[128 * 64];    // dword = i*64 + ((c4 ^ (i&7))<<2) + e
  __shared__ __align__(16) float Vr[128 * 64];    // row-major [i][d]
  __shared__ __align__(16) float p_lds[8][128];
  __shared__ __align__(16) float q_lds[8][64];

  const int tid = threadIdx.x, lane = tid & 63, w = tid >> 6;
  const size_t base = (size_t)b * SEQ;

  float m_s[16], sum_s[16], acc_s[16];
#pragma unroll
  for (int k = 0; k < 16; ++k) { m_s[k] = -INFINITY; sum_s[k] = 0.f; acc_s[k] = 0.f; }

  const int nchunks = rt + 1;
  for (int ch = 0; ch < nchunks; ++ch) {
    const int c0 = ch * 128;
    __syncthreads();   // previous chunk fully consumed
#pragma unroll
    for (int it = 0; it < 4; ++it) {
      const int idx = it * 512 + tid;          // 0..2047 = 128 keys x 16 f4-slots
      const int i = idx >> 4, c4 = idx & 15;
      const float4 kv = *(const float4*)&qkvf[(base + c0 + i) * 3072 + 1024 + h * 64 + c4 * 4];
      *(float4*)&Kc[i * 64 + ((c4 ^ (i & 7)) << 2)] = kv;
      const float4 vv = *(const float4*)&qkvf[(base + c0 + i) * 3072 + 2048 + h * 64 + c4 * 4];
      *(float4*)&Vr[i * 64 + c4 * 4] = vv;
    }
    __syncthreads();

#pragma unroll
    for (int k = 0; k < 16; ++k) {
      const int l = row0 + k * 8 + w;          // wave-uniform
      if (l < c0) continue;                    // no keys for this row in this chunk
      const int kend = min(l + 1 - c0, 128);

      q_lds[w][lane] = qkvf[(base + l) * 3072 + h * 64 + lane];
      __asm__ volatile("s_waitcnt lgkmcnt(0)" ::: "memory");

      // lane handles keys i = lane and i = 64+lane
      float s0 = 0.f, s1 = 0.f;
      const int sw0 = (lane & 7), sw1 = ((64 + lane) & 7);
#pragma unroll
      for (int c4 = 0; c4 < 16; ++c4) {
        const float4 qv  = *(const float4*)&q_lds[w][c4 * 4];
        const float4 k0v = *(const float4*)&Kc[lane * 64 + ((c4 ^ sw0) << 2)];
        s0 += k0v.x * qv.x + k0v.y * qv.y + k0v.z * qv.z + k0v.w * qv.w;
        const float4 k1v = *(const float4*)&Kc[(64 + lane) * 64 + ((c4 ^ sw1) << 2)];
        s1 += k1v.x * qv.x + k1v.y * qv.y + k1v.z * qv.z + k1v.w * qv.w;
      }
      const bool v0 = (lane < kend) && (amask[b * SEQ + c0 + lane] != 0);
      const bool v1 = (64 + lane < kend) && (amask[b * SEQ + c0 + 64 + lane] != 0);
      s0 = v0 ? (30.f * tanhf(s0 * 0.125f)) : -1e9f;
      s1 = v1 ? (30.f * tanhf(s1 * 0.125f)) : -1e9f;

      float cmx = fmaxf(s0, s1);
#pragma unroll
      for (int o = 32; o; o >>= 1) cmx = fmaxf(cmx, __shfl_xor(cmx, o));
      const float nm = fmaxf(m_s[k], cmx);
      const float p0 = expf(s0 - nm), p1 = expf(s1 - nm);   // masked -> 0
      p_lds[w][lane] = p0;
      p_lds[w][64 + lane] = p1;
      float cs = p0 + p1;
#pragma unroll
      for (int o = 32; o; o >>= 1) cs += __shfl_xor(cs, o);
      const float rs = expf(m_s[k] - nm);      // -inf -> 0 on first chunk
      m_s[k] = nm;
      sum_s[k] = sum_s[k] * rs + cs;
      float a = acc_s[k] * rs;
      __asm__ volatile("s_waitcnt lgkmcnt(0)" ::: "memory");

      const int nk4 = (kend + 3) >> 2;         // p beyond kend is 0 (freshly written)
      for (int i4 = 0; i4 < nk4; ++i4) {
        const float4 pv = *(const float4*)&p_lds[w][i4 * 4];
        a += pv.x * Vr[(i4 * 4 + 0) * 64 + lane]
           + pv.y * Vr[(i4 * 4 + 1) * 64 + lane]
           + pv.z * Vr[(i4 * 4 + 2) * 64 + lane]
           + pv.w * Vr[(i4 * 4 + 3) * 64 + lane];
      }
      acc_s[k] = a;
    }
  }

#pragma unroll
  for (int k = 0; k < 16; ++k) {
    const int l = row0 + k * 8 + w;
    const float o = acc_s[k] / sum_s[k];
    unsigned short hh, ll;
    split2(o, hh, ll);
    out2[(base + l) * 2048 + h * 64 + lane] = hh;
    out2[(base + l) * 2048 + 1024 + h * 64 + lane] = ll;
  }
}

extern "C" void kernel_launch(void* const* d_in, const int* in_sizes, int n_in,
                              void* d_out, int out_size, void* d_ws, size_t ws_size,
                              hipStream_t stream) {
  const int*   ids       = (const int*)d_in[0];
  const int*   amask     = (const int*)d_in[1];
  const float* W_vocab   = (const float*)d_in[2];
  const float* W_devocab = (const float*)d_in[3];
  const float* WQ        = (const float*)d_in[4];
  const float* WK        = (const float*)d_in[5];
  const float* WV        = (const float*)d_in[6];
  const float* W_O       = (const float*)d_in[7];
  const float* gamma1    = (const float*)d_in[8];
  const float* beta1     = (const float*)d_in[9];
  const float* gamma2    = (const float*)d_in[10];
  const float* beta2     = (const float*)d_in[11];
  const float* W_up      = (const float*)d_in[12];
  const float* b_up      = (const float*)d_in[13];
  const float* W_down    = (const float*)d_in[14];
  const float* b_down    = (const float*)d_in[15];
  const float* gamma_f   = (const float*)d_in[16];
  const float* beta_f    = (const float*)d_in[17];

  char* p = (char*)d_ws;
  auto alloc = [&](size_t bytes) { char* r = p; p += (bytes + 255) & ~(size_t)255; return r; };

  unsigned short* WQKV2 = (unsigned short*)alloc((size_t)NLAYERS * 3072 * 2048 * 2);
  unsigned short* WO2   = (unsigned short*)alloc((size_t)NLAYERS * 1024 * 2048 * 2);
  unsigned short* WUp2  = (unsigned short*)alloc((size_t)NLAYERS * 4096 * 2048 * 2);
  unsigned short* WDn2  = (unsigned short*)alloc((size_t)NLAYERS * 1024 * 8192 * 2);
  unsigned short* WDev1 = (unsigned short*)alloc((size_t)VOCAB * 1024 * 2);
  float* x    = (float*)alloc((size_t)NTOK * 1024 * 4);
  float* z1   = (float*)alloc((size_t)NTOK * 1024 * 4);
  unsigned short* u2    = (unsigned short*)alloc((size_t)NTOK * 2048 * 2);   // also v1 / xf
  float* qkvf = (float*)alloc((size_t)NTOK * 3072 * 4);
  unsigned short* attn2 = (unsigned short*)alloc((size_t)NTOK * 2048 * 2);
  unsigned short* h2    = (unsigned short*)alloc((size_t)NTOK * 8192 * 2);
  (void)ws_size; (void)in_sizes; (void)n_in; (void)out_size;

  // ---- weight prep (hi/lo split planes) ----
  cvt_qkv_split<<<2048, 256, 0, stream>>>(WQ, WK, WV, WQKV2);
  cvt_split<<<2048, 256, 0, stream>>>(W_O, WO2, (long)NLAYERS * 1024, 1024);
  transpose_cvt_split<<<dim3(4096 / 32, 1024 / 32, NLAYERS), 256, 0, stream>>>(W_up, WUp2, 1024, 4096);
  transpose_cvt_split<<<dim3(1024 / 32, 4096 / 32, NLAYERS), 256, 0, stream>>>(W_down, WDn2, 4096, 1024);
  transpose_cvt<<<dim3(VOCAB / 32, 1024 / 32, 1), 256, 0, stream>>>(W_devocab, WDev1, 1024, VOCAB);

  // ---- embedding ----
  embed_kernel<<<NTOK, 256, 0, stream>>>(ids, W_vocab, x);

  // ---- layers ----
  for (int l = 0; l < NLAYERS; ++l) {
    layernorm_split<<<NTOK, 256, 0, stream>>>(x, gamma1 + l * 1024, beta1 + l * 1024, u2);
    // fused QKV (split-3, f32 out): [4096,3072]
    gemm_bt<0, 3><<<dim3(3072 / 128, NTOK / 128), 256, 0, stream>>>(
        u2, WQKV2 + (size_t)l * 3072 * 2048, qkvf, nullptr, nullptr, nullptr,
        NTOK, 3072, 1024);
    attn_kernel<<<BATCH * NHEADS * 4, 512, 0, stream>>>(qkvf, amask, attn2);
    // z1 = x + attn @ W_O^T
    gemm_bt<2, 3><<<dim3(1024 / 128, NTOK / 128), 256, 0, stream>>>(
        attn2, WO2 + (size_t)l * 1024 * 2048, z1, nullptr, nullptr, x,
        NTOK, 1024, 1024);
    layernorm_split<<<NTOK, 256, 0, stream>>>(z1, gamma2 + l * 1024, beta2 + l * 1024, u2);
    // h = gelu(v1 @ W_up + b_up), hi/lo out
    gemm_bt<3, 3><<<dim3(4096 / 128, NTOK / 128), 256, 0, stream>>>(
        u2, WUp2 + (size_t)l * 4096 * 2048, nullptr, h2, b_up + l * 4096, nullptr,
        NTOK, 4096, 1024);
    // x = z1 + h @ W_down + b_down
    gemm_bt<4, 3><<<dim3(1024 / 128, NTOK / 128), 256, 0, stream>>>(
        h2, WDn2 + (size_t)l * 1024 * 8192, x, nullptr, b_down + l * 1024, z1,
        NTOK, 1024, 4096);
  }

  // ---- final LN + devocab (split-2: x hi/lo, W hi only) ----
  layernorm_split<<<NTOK, 256, 0, stream>>>(x, gamma_f, beta_f, u2);
  gemm_bt<0, 2><<<dim3(VOCAB / 128, NTOK / 128), 256, 0, stream>>>(
      u2, WDev1, (float*)d_out, nullptr, nullptr, nullptr,
      NTOK, VOCAB, 1024);
}